// Round 8
// baseline (3056.348 us; speedup 1.0000x reference)
//
#include <hip/hip_runtime.h>
#include <hip/hip_bf16.h>

constexpr int NG   = 8;          // graphs
constexpr int NPG  = 4096;       // nodes per graph
constexpr int NT   = NG * NPG;   // 32768 total nodes
constexpr int NS   = 2048;       // fps samples per graph
constexpr int GS   = NG * NS;    // 16384
constexpr int KN   = 64;         // max neighbors
constexpr int NE   = NG * 65536; // 524288 edges
constexpr int NC   = 13;         // classes
constexpr int NBW  = 508;        // worker blocks in phaseA

__device__ __forceinline__ float inp_val(const float* norm, const float* pos, const float* x,
                                         int node, int dim) {
  if (dim < 3) return norm[(size_t)node * 3 + dim];
  if (dim < 6) return pos[(size_t)node * 3 + (dim - 3)];
  return x[(size_t)node * 2 + (dim - 6)];
}

// ---- phase A: fps 2-graphs-per-block (blocks 0-3) + feat1 + deg1 (blocks 4..) ----
__global__ __launch_bounds__(512, 1) void phaseA_kernel(
    const float* __restrict__ pos, int* __restrict__ idxf, float* __restrict__ qpos,
    const float* __restrict__ norm, const float* __restrict__ x,
    const float* __restrict__ W1, float* __restrict__ t1,
    const int* __restrict__ ei, int* __restrict__ deg) {
  if (blockIdx.x >= 4) {
    // ---- workers: feat1 (grid-stride over nodes, 8 nodes per block-iter) ----
    int wb = blockIdx.x - 4;
    int sub = threadIdx.x >> 6;   // 0..7, one wave each
    int f = threadIdx.x & 63;
    __shared__ float row[8][8];
    for (int n0 = wb * 8; n0 < NT; n0 += NBW * 8) {
      int n = n0 + sub;
      if (f < 8) row[sub][f] = inp_val(norm, pos, x, n, f);
      // same-wave LDS write->read (lockstep; compiler inserts lgkmcnt wait)
      float acc = 0.f;
#pragma unroll
      for (int i = 0; i < 8; ++i) acc += row[sub][i] * W1[i * 64 + f];
      t1[(size_t)n * 64 + f] = acc;
    }
    // ---- workers: deg1 (grid-stride over edges) ----
    for (int e = wb * 512 + threadIdx.x; e < NE; e += NBW * 512)
      atomicAdd(&deg[ei[NE + e]], 1);
    return;
  }
  // ---- FPS: two graphs per block; waves 0-3 = graph A, waves 4-7 = graph B ----
  const int gsub = threadIdx.x >> 8;   // 0 or 1
  const int g = blockIdx.x * 2 + gsub;
  const int t = threadIdx.x & 255;     // tid within half
  const int wave = threadIdx.x >> 6;   // 0..7 (block-wide wave id)
  const int lane = threadIdx.x & 63;
  const int p0 = t * 16;
  __shared__ float4 sq[2][8];
  __shared__ int sidx[2][8];
  __shared__ float4 qrec[2][NS];   // 64 KB
  __shared__ int irec[2][NS];      // 16 KB
  const float* pg = pos + (size_t)g * NPG * 3;

  float a[48];
  {
    const float4* pg4 = reinterpret_cast<const float4*>(pg + (size_t)p0 * 3);
#pragma unroll
    for (int j = 0; j < 12; ++j) {
      float4 tt = pg4[j];
      a[4 * j + 0] = tt.x; a[4 * j + 1] = tt.y; a[4 * j + 2] = tt.z; a[4 * j + 3] = tt.w;
    }
  }
  float px[16], py[16], pz[16], mind[16];
#pragma unroll
  for (int i = 0; i < 16; ++i) {
    px[i] = a[3 * i]; py[i] = a[3 * i + 1]; pz[i] = a[3 * i + 2];
    mind[i] = __int_as_float(0x7f800000);  // +inf
  }
  float cx = pg[0], cy = pg[1], cz = pg[2];
  int idx_sel = 0;  // maintained by t==0 of each half

  for (int s = 0; s < NS; ++s) {
    if (t == 0) { irec[gsub][s] = idx_sel; qrec[gsub][s] = make_float4(cx, cy, cz, 0.f); }
    // exact ref rounding (no fma); strict > keeps first occurrence
    float bestv = -1.f, bx = 0.f, by = 0.f, bz = 0.f;
    int bi = 0;
#pragma unroll
    for (int i = 0; i < 16; ++i) {
      float dx = __fsub_rn(px[i], cx);
      float dy = __fsub_rn(py[i], cy);
      float dz = __fsub_rn(pz[i], cz);
      float dd = __fadd_rn(__fadd_rn(__fmul_rn(dx, dx), __fmul_rn(dy, dy)), __fmul_rn(dz, dz));
      float nm = fminf(mind[i], dd);
      mind[i] = nm;
      bool gt = nm > bestv;
      bestv = gt ? nm : bestv;
      bx = gt ? px[i] : bx;
      by = gt ? py[i] : by;
      bz = gt ? pz[i] : bz;
      bi = gt ? i : bi;
    }
    // wave-wide f32 max via DPP; result lands in lane 63 (wave is entirely within one graph)
    float v = bestv;
    v = fmaxf(v, __int_as_float(__builtin_amdgcn_update_dpp(0, __float_as_int(v), 0x111, 0xF, 0xF, true)));
    v = fmaxf(v, __int_as_float(__builtin_amdgcn_update_dpp(0, __float_as_int(v), 0x112, 0xF, 0xF, true)));
    v = fmaxf(v, __int_as_float(__builtin_amdgcn_update_dpp(0, __float_as_int(v), 0x114, 0xF, 0xF, true)));
    v = fmaxf(v, __int_as_float(__builtin_amdgcn_update_dpp(0, __float_as_int(v), 0x118, 0xF, 0xF, true)));
    v = fmaxf(v, __int_as_float(__builtin_amdgcn_update_dpp(0, __float_as_int(v), 0x142, 0xF, 0xF, true)));
    v = fmaxf(v, __int_as_float(__builtin_amdgcn_update_dpp(0, __float_as_int(v), 0x143, 0xF, 0xF, true)));
    int maxbits = __builtin_amdgcn_readlane(__float_as_int(v), 63);
    float wavemax = __int_as_float(maxbits);
    unsigned long long ball = __ballot(bestv == wavemax);
    int winner = __ffsll(ball) - 1;  // lowest lane = lowest index (contiguous ownership)
    int b = s & 1;
    if (lane == winner) {
      sq[b][wave] = make_float4(bx, by, bz, wavemax);
      sidx[b][wave] = p0 + bi;
    }
    __syncthreads();  // ONE barrier serves both graphs
    const int base = gsub * 4;
    float4 q0 = sq[b][base + 0], q1 = sq[b][base + 1];
    float4 q2 = sq[b][base + 2], q3 = sq[b][base + 3];
    float4 qs = q3;
    if (q2.w >= qs.w) qs = q2;   // >= toward lower wave = lowest index on ties
    if (q1.w >= qs.w) qs = q1;
    if (q0.w >= qs.w) qs = q0;
    cx = qs.x; cy = qs.y; cz = qs.z;
    if (t == 0) {  // resolve index for the record (off critical path)
      int i0 = sidx[b][base + 0], i1 = sidx[b][base + 1];
      int i2 = sidx[b][base + 2], i3 = sidx[b][base + 3];
      float r = q3.w; int is = i3;
      if (q2.w >= r) { r = q2.w; is = i2; }
      if (q1.w >= r) { r = q1.w; is = i1; }
      if (q0.w >= r) { r = q0.w; is = i0; }
      idx_sel = is;
    }
  }
  __syncthreads();
  // bulk write of both graphs' per-step outputs
  for (int j = t; j < NS; j += 256) {
    idxf[g * NS + j] = g * NPG + irec[gsub][j];
    float4 q = qrec[gsub][j];
    size_t m = (size_t)(g * NS + j) * 3;
    qpos[m + 0] = q.x; qpos[m + 1] = q.y; qpos[m + 2] = q.z;
  }
}

// ---------------- feature transforms ----------------
__global__ void feat2_kernel(const float* __restrict__ h1, const float* __restrict__ norm,
                             const float* __restrict__ pos, const float* __restrict__ x,
                             const float* __restrict__ W2, float* __restrict__ t2) {
  int n = blockIdx.x, f = threadIdx.x;  // 128 threads
  __shared__ float row[72];
  if (f < 64) row[f] = h1[(size_t)n * 64 + f];
  else if (f < 72) row[f] = inp_val(norm, pos, x, n, f - 64);
  __syncthreads();
  float acc = 0.f;
#pragma unroll 8
  for (int i = 0; i < 72; ++i) acc += row[i] * W2[i * 128 + f];
  t2[(size_t)n * 128 + f] = acc;
}

// feat3 (blocks 0..GS-1) fused with deg2 (blocks GS..GS+NE/256-1)
__global__ void featdeg_kernel(const float* __restrict__ xint, const int* __restrict__ idxf,
                               const float* __restrict__ norm, const float* __restrict__ pos,
                               const float* __restrict__ x, const float* __restrict__ W3,
                               float* __restrict__ t3,
                               const int* __restrict__ ei, const int* __restrict__ mp,
                               int* __restrict__ deg) {
  if (blockIdx.x >= GS) {
    int e = (blockIdx.x - GS) * 256 + threadIdx.x;  // exactly NE threads
    int ns = mp[ei[e]], nd = mp[ei[NE + e]];
    if (ns >= 0 && nd >= 0) atomicAdd(&deg[nd], 1);
    return;
  }
  int m = blockIdx.x, f = threadIdx.x;  // 256 threads
  __shared__ float row[139];
  if (f < 131) row[f] = xint[(size_t)m * 131 + f];
  else if (f < 139) { int node = idxf[m]; row[f] = inp_val(norm, pos, x, node, f - 131); }
  __syncthreads();
  float acc = 0.f;
#pragma unroll 8
  for (int i = 0; i < 139; ++i) acc += row[i] * W3[i * 256 + f];
  t3[(size_t)m * 256 + f] = acc;
}

// ---------------- CSR build (edge_index int32: row0=src [0,NE), row1=dst [NE,2NE)) ----
__global__ void fill1_kernel(const int* __restrict__ ei, const int* __restrict__ off,
                             int* __restrict__ cur, int* __restrict__ el) {
  int e = blockIdx.x * 256 + threadIdx.x;
  if (e < NE) {
    int sN = ei[e], dN = ei[NE + e];
    int p = off[dN] + atomicAdd(&cur[dN], 1);
    el[p] = sN;
  }
}

__global__ void fill2_kernel(const int* __restrict__ ei, const int* __restrict__ mp,
                             const int* __restrict__ off, int* __restrict__ cur,
                             int* __restrict__ el) {
  int e = blockIdx.x * 256 + threadIdx.x;
  if (e < NE) {
    int ns = mp[ei[e]], nd = mp[ei[NE + e]];
    if (ns >= 0 && nd >= 0) {
      int p = off[nd] + atomicAdd(&cur[nd], 1);
      el[p] = ns;
    }
  }
}

// single-block exclusive scan, n <= 32768, writes out[0..n]
__global__ __launch_bounds__(1024) void scan_kernel(const int* __restrict__ in,
                                                    int* __restrict__ out, int n) {
  __shared__ int ls[1024];
  int tid = threadIdx.x;
  int per = (n + 1023) >> 10;
  int base = tid * per;
  int s = 0;
  for (int i = 0; i < per; ++i) { int idx = base + i; if (idx < n) s += in[idx]; }
  ls[tid] = s;
  __syncthreads();
  for (int d = 1; d < 1024; d <<= 1) {
    int v = (tid >= d) ? ls[tid - d] : 0;
    __syncthreads();
    ls[tid] += v;
    __syncthreads();
  }
  int excl = (tid == 0) ? 0 : ls[tid - 1];
  for (int i = 0; i < per; ++i) {
    int idx = base + i;
    if (idx < n) { out[idx] = excl; excl += in[idx]; }
  }
  if (tid == 1023) out[n] = ls[1023];
}

// gather-side GCN aggregation: out[node,f] = relu(b[f] + sum_{src in list} t[src,f])
__global__ void agg_kernel(const float* __restrict__ t, const int* __restrict__ off,
                           const int* __restrict__ el, const float* __restrict__ b,
                           float* __restrict__ out, int F) {
  int node = blockIdx.x, f = threadIdx.x;
  int e0 = off[node], e1 = off[node + 1];
  float acc = 0.f;
  for (int j = e0; j < e1; ++j) acc += t[(size_t)el[j] * F + f];
  out[(size_t)node * F + f] = fmaxf(acc + b[f], 0.f);
}

// ---------------- radius neighbors (first K lowest-index within R) + mapset ----------------
__global__ __launch_bounds__(256) void radius_kernel(const float* __restrict__ pos,
                                                     const float* __restrict__ qpos,
                                                     int* __restrict__ cols,
                                                     int* __restrict__ cnt,
                                                     const int* __restrict__ idxf,
                                                     int* __restrict__ mp) {
  const int g = blockIdx.x;
  __shared__ float sx[NPG], sy[NPG], sz[NPG];
  const float* pg = pos + (size_t)g * NPG * 3;
  for (int i = threadIdx.x; i < NPG * 3; i += 256) {
    float v = pg[i]; int node = i / 3, c = i - node * 3;
    if (c == 0) sx[node] = v; else if (c == 1) sy[node] = v; else sz[node] = v;
  }
  __syncthreads();
  int m = g * NS + blockIdx.y * 256 + threadIdx.x;
  mp[idxf[m]] = m;  // fused mapset (threads <-> samples 1:1 over the grid)
  float qx = qpos[(size_t)m * 3], qy = qpos[(size_t)m * 3 + 1], qz = qpos[(size_t)m * 3 + 2];
  int* out = cols + (size_t)m * KN;
  int c = 0;
  for (int i = 0; i < NPG; ++i) {
    float dx = __fsub_rn(sx[i], qx);
    float dy = __fsub_rn(sy[i], qy);
    float dz = __fsub_rn(sz[i], qz);
    float d2 = __fadd_rn(__fadd_rn(__fmul_rn(dx, dx), __fmul_rn(dy, dy)), __fmul_rn(dz, dz));
    if (d2 < 0.16f) {
      out[c++] = i;
      if (c == KN) break;
    }
  }
  cnt[m] = c;
}

// ---------------- PointConv: max over neighbors of [h2[c], p[c]-q] ----------------
__global__ __launch_bounds__(64) void pointconv_kernel(const float* __restrict__ h2,
                                                       const float* __restrict__ pos,
                                                       const float* __restrict__ qpos,
                                                       const int* __restrict__ cols,
                                                       const int* __restrict__ cnt,
                                                       float* __restrict__ xint) {
  int m = blockIdx.x, t = threadIdx.x;
  int g = m / NS;
  int n = cnt[m];
  const int* cl = cols + (size_t)m * KN;
  float m0 = -INFINITY, m1 = -INFINITY, mp = -INFINITY;
  for (int k = 0; k < n; ++k) {
    int c = cl[k];
    size_t base = (size_t)(g * NPG + c);
    m0 = fmaxf(m0, h2[base * 128 + t]);
    m1 = fmaxf(m1, h2[base * 128 + 64 + t]);
    if (t < 3) mp = fmaxf(mp, pos[base * 3 + t]);
  }
  float* xo = xint + (size_t)m * 131;
  xo[t] = m0;
  xo[64 + t] = m1;
  if (t < 3) xo[128 + t] = __fsub_rn(mp, qpos[(size_t)m * 3 + t]);
}

// ---------------- pooling + head ----------------
__global__ void pool_kernel(const float* __restrict__ h3, float* __restrict__ pooled) {
  int g = blockIdx.x, ch = blockIdx.y, f = threadIdx.x;  // 256 threads
  float mx = 0.f;  // h3 >= 0 (relu)
  size_t base = ((size_t)g * NS + (size_t)ch * 256) * 256 + f;
  for (int s = 0; s < 256; ++s) mx = fmaxf(mx, h3[base + (size_t)s * 256]);
  atomicMax((int*)pooled + g * 256 + f, __float_as_int(mx));
}

__global__ void head_kernel(const float* __restrict__ pooled, const float* __restrict__ lw,
                            const float* __restrict__ lb, float* __restrict__ outp) {
  __shared__ float lg[NG * NC];
  int t = threadIdx.x;  // 128 threads
  if (t < NG * NC) {
    int g = t / NC, c = t % NC;
    float acc = lb[c];
    for (int k = 0; k < 256; ++k) acc += pooled[g * 256 + k] * lw[k * NC + c];
    lg[t] = acc;
  }
  __syncthreads();
  if (t < NG) {
    int g = t;
    float mx = -INFINITY;
    for (int c = 0; c < NC; ++c) mx = fmaxf(mx, lg[g * NC + c]);
    float sum = 0.f;
    for (int c = 0; c < NC; ++c) sum += expf(lg[g * NC + c] - mx);
    float lse = logf(sum);
    float ov[NC];
    float mx2 = -INFINITY;
    for (int c = 0; c < NC; ++c) {
      ov[c] = lg[g * NC + c] - mx - lse;
      outp[g * NC + c] = ov[c];
      mx2 = fmaxf(mx2, ov[c]);
    }
    float s2 = 0.f;
    for (int c = 0; c < NC; ++c) s2 += expf(ov[c] - mx2);
    for (int c = 0; c < NC; ++c) outp[NG * NC + g * NC + c] = expf(ov[c] - mx2) / s2;
  }
}

extern "C" void kernel_launch(void* const* d_in, const int* in_sizes, int n_in,
                              void* d_out, int out_size, void* d_ws, size_t ws_size,
                              hipStream_t stream) {
  const float* norm = (const float*)d_in[0];
  const float* pos  = (const float*)d_in[1];
  const float* x    = (const float*)d_in[2];
  const int* ei     = (const int*)d_in[3];   // int32! row0 = src, row1 = dst
  // d_in[4] = batch (int32, unused)
  const float* W1 = (const float*)d_in[5];
  const float* b1 = (const float*)d_in[6];
  const float* W2 = (const float*)d_in[7];
  const float* b2 = (const float*)d_in[8];
  const float* W3 = (const float*)d_in[9];
  const float* b3 = (const float*)d_in[10];
  const float* lw = (const float*)d_in[11];
  const float* lb = (const float*)d_in[12];
  float* outp = (float*)d_out;

  char* w = (char*)d_ws;
  size_t o = 0;
  auto alloc = [&](size_t bytes) -> void* {
    void* p = w + o;
    o = (o + bytes + 255) & ~(size_t)255;
    return p;
  };
  // A: t1 (NT*64) -> t2 (NT*128) -> t3 (GS*256, same byte count)
  float* A    = (float*)alloc((size_t)NT * 128 * 4);
  // B: h1 (NT*64) -> h2 (NT*128) -> h3 (GS*256)
  float* Bf   = (float*)alloc((size_t)NT * 128 * 4);
  float* xint = (float*)alloc((size_t)GS * 131 * 4);
  int* cols   = (int*)alloc((size_t)GS * KN * 4);
  int* cnt    = (int*)alloc((size_t)GS * 4);
  int* deg1   = (int*)alloc((size_t)NT * 4);
  int* off1   = (int*)alloc((size_t)(NT + 1) * 4);
  int* cur1   = (int*)alloc((size_t)NT * 4);
  int* el1    = (int*)alloc((size_t)NE * 4);
  int* deg2   = (int*)alloc((size_t)GS * 4);
  int* off2   = (int*)alloc((size_t)(GS + 1) * 4);
  int* cur2   = (int*)alloc((size_t)GS * 4);
  int* el2    = (int*)alloc((size_t)NE * 4);
  int* idxf   = (int*)alloc((size_t)GS * 4);
  float* qpos = (float*)alloc((size_t)GS * 3 * 4);
  int* mapv   = (int*)alloc((size_t)NT * 4);
  float* pooled = (float*)alloc((size_t)NG * 256 * 4);

  hipMemsetAsync(deg1, 0, (size_t)NT * 4, stream);
  hipMemsetAsync(cur1, 0, (size_t)NT * 4, stream);
  hipMemsetAsync(deg2, 0, (size_t)GS * 4, stream);
  hipMemsetAsync(cur2, 0, (size_t)GS * 4, stream);
  hipMemsetAsync(mapv, 0xFF, (size_t)NT * 4, stream);  // -1
  hipMemsetAsync(pooled, 0, (size_t)NG * 256 * 4, stream);

  // phase A: fps (2 graphs/block) + feat1 + deg1 concurrently
  phaseA_kernel<<<4 + NBW, 512, 0, stream>>>(pos, idxf, qpos, norm, x, W1, A, ei, deg1);
  // layer 1 chain
  scan_kernel<<<1, 1024, 0, stream>>>(deg1, off1, NT);
  fill1_kernel<<<NE / 256, 256, 0, stream>>>(ei, off1, cur1, el1);
  agg_kernel<<<NT, 64, 0, stream>>>(A, off1, el1, b1, Bf, 64);
  // layer 2
  feat2_kernel<<<NT, 128, 0, stream>>>(Bf, norm, pos, x, W2, A);
  agg_kernel<<<NT, 128, 0, stream>>>(A, off1, el1, b2, Bf, 128);
  // neighborhoods (radius + fused mapset)
  radius_kernel<<<dim3(NG, NS / 256), 256, 0, stream>>>(pos, qpos, cols, cnt, idxf, mapv);
  pointconv_kernel<<<GS, 64, 0, stream>>>(Bf, pos, qpos, cols, cnt, xint);
  // feat3 + deg2 fused
  featdeg_kernel<<<GS + NE / 256, 256, 0, stream>>>(xint, idxf, norm, pos, x, W3, A,
                                                    ei, mapv, deg2);
  scan_kernel<<<1, 1024, 0, stream>>>(deg2, off2, GS);
  fill2_kernel<<<NE / 256, 256, 0, stream>>>(ei, mapv, off2, cur2, el2);
  // layer 3
  agg_kernel<<<GS, 256, 0, stream>>>(A, off2, el2, b3, Bf, 256);
  // pool + head
  pool_kernel<<<dim3(NG, NS / 256), 256, 0, stream>>>(Bf, pooled);
  head_kernel<<<1, 128, 0, stream>>>(pooled, lw, lb, outp);
}

// Round 9
// 2165.689 us; speedup vs baseline: 1.4113x; 1.4113x over previous
//
#include <hip/hip_runtime.h>
#include <hip/hip_bf16.h>

constexpr int NG   = 8;          // graphs
constexpr int NPG  = 4096;       // nodes per graph
constexpr int NT   = NG * NPG;   // 32768 total nodes
constexpr int NS   = 2048;       // fps samples per graph
constexpr int GS   = NG * NS;    // 16384
constexpr int KN   = 64;         // max neighbors
constexpr int NE   = NG * 65536; // 524288 edges
constexpr int NC   = 13;         // classes
constexpr int NWORK = 248;       // worker blocks in phaseA (blocks 8..255)

__device__ __forceinline__ float inp_val(const float* norm, const float* pos, const float* x,
                                         int node, int dim) {
  if (dim < 3) return norm[(size_t)node * 3 + dim];
  if (dim < 6) return pos[(size_t)node * 3 + (dim - 3)];
  return x[(size_t)node * 2 + (dim - 6)];
}

// agent-scope arrive-and-wait barrier among the NWORK worker blocks (co-resident via
// cooperative launch; fps blocks never touch it)
__device__ __forceinline__ void wbar(int* ctrs, int k, int target) {
  __syncthreads();
  __threadfence();  // make this block's stores visible device-wide
  if (threadIdx.x == 0) {
    __hip_atomic_fetch_add(&ctrs[k], 1, __ATOMIC_RELEASE, __HIP_MEMORY_SCOPE_AGENT);
    while (__hip_atomic_load(&ctrs[k], __ATOMIC_ACQUIRE, __HIP_MEMORY_SCOPE_AGENT) < target)
      __builtin_amdgcn_s_sleep(16);
  }
  __syncthreads();
}

// ---- phase A (cooperative, 256 blocks x 256 thr) ----
// blocks 0-7: fps (round-7 structure, unchanged bit-exact arithmetic)
// blocks 8-255: feat1+deg1 -> [bar] -> scan(off1) -> [bar] -> fill1 -> [bar]
//               -> fused agg1+feat2 -> [bar] -> agg2   (all hidden under fps)
__global__ __launch_bounds__(256, 1) void phaseA_kernel(
    const float* __restrict__ pos, int* __restrict__ idxf, float* __restrict__ qpos,
    const float* __restrict__ norm, const float* __restrict__ x,
    const float* __restrict__ W1, float* __restrict__ t1,
    const int* __restrict__ ei, int* __restrict__ deg,
    int* __restrict__ off1, int* __restrict__ cur1, int* __restrict__ el1,
    const float* __restrict__ b1, const float* __restrict__ W2, float* __restrict__ t2,
    const float* __restrict__ b2, float* __restrict__ h2,
    int* __restrict__ wctr) {
  if (blockIdx.x >= 8) {
    // ================= workers =================
    const int wb = blockIdx.x - 8;
    const int sub = threadIdx.x >> 6;   // 0..3 (one wave each)
    const int f = threadIdx.x & 63;
    __shared__ float wrow[4][80];
    __shared__ int sscan[256];
    // stage 0: feat1 (t1 = inp @ W1) + deg1
    for (int n0 = wb * 4; n0 < NT; n0 += NWORK * 4) {
      int n = n0 + sub;
      if (f < 8) wrow[sub][f] = inp_val(norm, pos, x, n, f);
      float acc = 0.f;  // same-wave LDS write->read, lockstep
#pragma unroll
      for (int i = 0; i < 8; ++i) acc += wrow[sub][i] * W1[i * 64 + f];
      t1[(size_t)n * 64 + f] = acc;
    }
    for (int e = wb * 256 + threadIdx.x; e < NE; e += NWORK * 256)
      atomicAdd(&deg[ei[NE + e]], 1);
    wbar(wctr, 0, NWORK);
    // stage 1: exclusive scan deg -> off1 (block wb==0 only; hidden under fps anyway)
    if (wb == 0) {
      int t = threadIdx.x, base = t * 128, s = 0;
      for (int i = 0; i < 128; ++i) s += deg[base + i];
      sscan[t] = s;
      __syncthreads();
      for (int d = 1; d < 256; d <<= 1) {
        int v = (t >= d) ? sscan[t - d] : 0;
        __syncthreads();
        sscan[t] += v;
        __syncthreads();
      }
      int excl = (t == 0) ? 0 : sscan[t - 1];
      for (int i = 0; i < 128; ++i) { off1[base + i] = excl; excl += deg[base + i]; }
      if (t == 255) off1[NT] = sscan[255];
    }
    wbar(wctr, 1, NWORK);
    // stage 2: fill1 (CSR edge lists)
    for (int e = wb * 256 + threadIdx.x; e < NE; e += NWORK * 256) {
      int sN = ei[e], dN = ei[NE + e];
      int p = off1[dN] + atomicAdd(&cur1[dN], 1);
      el1[p] = sN;
    }
    wbar(wctr, 2, NWORK);
    // stage 3: fused agg1 (h1 = relu(sum t1 + b1)) + feat2 (t2 = [h1,inp] @ W2); h1 stays in LDS
    for (int n0 = wb * 4; n0 < NT; n0 += NWORK * 4) {
      int n = n0 + sub;
      int e0 = off1[n], e1 = off1[n + 1];
      float acc = 0.f;
      for (int j = e0; j < e1; ++j) acc += t1[(size_t)el1[j] * 64 + f];
      wrow[sub][f] = fmaxf(acc + b1[f], 0.f);
      if (f < 8) wrow[sub][64 + f] = inp_val(norm, pos, x, n, f);
      float a0 = 0.f, a1 = 0.f;  // lockstep within wave; uniform loop bounds
#pragma unroll 8
      for (int i = 0; i < 72; ++i) {
        float r = wrow[sub][i];
        a0 += r * W2[i * 128 + f];
        a1 += r * W2[i * 128 + 64 + f];
      }
      t2[(size_t)n * 128 + f] = a0;
      t2[(size_t)n * 128 + 64 + f] = a1;
    }
    wbar(wctr, 3, NWORK);
    // stage 4: agg2 (h2 = relu(sum t2 + b2))
    {
      const int f2 = threadIdx.x & 127, sub2 = threadIdx.x >> 7;
      for (int n0 = wb * 2; n0 < NT; n0 += NWORK * 2) {
        int n = n0 + sub2;
        int e0 = off1[n], e1 = off1[n + 1];
        float acc = 0.f;
        for (int j = e0; j < e1; ++j) acc += t2[(size_t)el1[j] * 128 + f2];
        h2[(size_t)n * 128 + f2] = fmaxf(acc + b2[f2], 0.f);
      }
    }
    return;
  }
  // ================= FPS (unchanged round-7 code) =================
  const int g = blockIdx.x;
  __shared__ float4 sq[2][4];
  __shared__ int sidx[2][4];
  __shared__ float4 qrec[NS];  // 32 KB
  __shared__ int irec[NS];     // 8 KB
  const float* pg = pos + (size_t)g * NPG * 3;
  const int tid = threadIdx.x;
  const int wave = tid >> 6, lane = tid & 63;
  const int p0 = tid * 16;

  float a[48];
  {
    const float4* pg4 = reinterpret_cast<const float4*>(pg + (size_t)p0 * 3);
#pragma unroll
    for (int j = 0; j < 12; ++j) {
      float4 t = pg4[j];
      a[4 * j + 0] = t.x; a[4 * j + 1] = t.y; a[4 * j + 2] = t.z; a[4 * j + 3] = t.w;
    }
  }
  float px[16], py[16], pz[16], mind[16];
#pragma unroll
  for (int i = 0; i < 16; ++i) {
    px[i] = a[3 * i]; py[i] = a[3 * i + 1]; pz[i] = a[3 * i + 2];
    mind[i] = __int_as_float(0x7f800000);  // +inf
  }
  float cx = pg[0], cy = pg[1], cz = pg[2];
  int idx_sel = 0;  // maintained by tid 0

  for (int s = 0; s < NS; ++s) {
    if (tid == 0) { irec[s] = idx_sel; qrec[s] = make_float4(cx, cy, cz, 0.f); }
    float bestv = -1.f, bx = 0.f, by = 0.f, bz = 0.f;
    int bi = 0;
#pragma unroll
    for (int i = 0; i < 16; ++i) {
      float dx = __fsub_rn(px[i], cx);
      float dy = __fsub_rn(py[i], cy);
      float dz = __fsub_rn(pz[i], cz);
      float dd = __fadd_rn(__fadd_rn(__fmul_rn(dx, dx), __fmul_rn(dy, dy)), __fmul_rn(dz, dz));
      float nm = fminf(mind[i], dd);
      mind[i] = nm;
      bool gt = nm > bestv;   // strict > keeps first occurrence
      bestv = gt ? nm : bestv;
      bx = gt ? px[i] : bx;
      by = gt ? py[i] : by;
      bz = gt ? pz[i] : bz;
      bi = gt ? i : bi;
    }
    float v = bestv;
    v = fmaxf(v, __int_as_float(__builtin_amdgcn_update_dpp(0, __float_as_int(v), 0x111, 0xF, 0xF, true)));
    v = fmaxf(v, __int_as_float(__builtin_amdgcn_update_dpp(0, __float_as_int(v), 0x112, 0xF, 0xF, true)));
    v = fmaxf(v, __int_as_float(__builtin_amdgcn_update_dpp(0, __float_as_int(v), 0x114, 0xF, 0xF, true)));
    v = fmaxf(v, __int_as_float(__builtin_amdgcn_update_dpp(0, __float_as_int(v), 0x118, 0xF, 0xF, true)));
    v = fmaxf(v, __int_as_float(__builtin_amdgcn_update_dpp(0, __float_as_int(v), 0x142, 0xF, 0xF, true)));
    v = fmaxf(v, __int_as_float(__builtin_amdgcn_update_dpp(0, __float_as_int(v), 0x143, 0xF, 0xF, true)));
    int maxbits = __builtin_amdgcn_readlane(__float_as_int(v), 63);
    float wavemax = __int_as_float(maxbits);
    unsigned long long ball = __ballot(bestv == wavemax);
    int winner = __ffsll(ball) - 1;  // lowest lane = lowest index (contiguous ownership)
    int b = s & 1;
    if (lane == winner) {
      sq[b][wave] = make_float4(bx, by, bz, wavemax);
      sidx[b][wave] = p0 + bi;
    }
    __syncthreads();
    float4 q0 = sq[b][0], q1 = sq[b][1], q2 = sq[b][2], q3 = sq[b][3];
    float4 qs = q3;
    if (q2.w >= qs.w) qs = q2;   // >= toward lower wave = lowest index on ties
    if (q1.w >= qs.w) qs = q1;
    if (q0.w >= qs.w) qs = q0;
    cx = qs.x; cy = qs.y; cz = qs.z;
    if (tid == 0) {  // resolve record index off the critical path
      int i0 = sidx[b][0], i1 = sidx[b][1], i2 = sidx[b][2], i3 = sidx[b][3];
      float r = q3.w; int is = i3;
      if (q2.w >= r) { r = q2.w; is = i2; }
      if (q1.w >= r) { r = q1.w; is = i1; }
      if (q0.w >= r) { r = q0.w; is = i0; }
      idx_sel = is;
    }
  }
  __syncthreads();
  for (int j = tid; j < NS; j += 256) {
    idxf[g * NS + j] = g * NPG + irec[j];
    float4 q = qrec[j];
    size_t m = (size_t)(g * NS + j) * 3;
    qpos[m + 0] = q.x; qpos[m + 1] = q.y; qpos[m + 2] = q.z;
  }
}

// feat3 (blocks 0..GS-1) fused with deg2 (blocks GS..GS+NE/256-1)
__global__ void featdeg_kernel(const float* __restrict__ xint, const int* __restrict__ idxf,
                               const float* __restrict__ norm, const float* __restrict__ pos,
                               const float* __restrict__ x, const float* __restrict__ W3,
                               float* __restrict__ t3,
                               const int* __restrict__ ei, const int* __restrict__ mp,
                               int* __restrict__ deg) {
  if (blockIdx.x >= GS) {
    int e = (blockIdx.x - GS) * 256 + threadIdx.x;  // exactly NE threads
    int ns = mp[ei[e]], nd = mp[ei[NE + e]];
    if (ns >= 0 && nd >= 0) atomicAdd(&deg[nd], 1);
    return;
  }
  int m = blockIdx.x, f = threadIdx.x;  // 256 threads
  __shared__ float row[139];
  if (f < 131) row[f] = xint[(size_t)m * 131 + f];
  else if (f < 139) { int node = idxf[m]; row[f] = inp_val(norm, pos, x, node, f - 131); }
  __syncthreads();
  float acc = 0.f;
#pragma unroll 8
  for (int i = 0; i < 139; ++i) acc += row[i] * W3[i * 256 + f];
  t3[(size_t)m * 256 + f] = acc;
}

__global__ void fill2_kernel(const int* __restrict__ ei, const int* __restrict__ mp,
                             const int* __restrict__ off, int* __restrict__ cur,
                             int* __restrict__ el) {
  int e = blockIdx.x * 256 + threadIdx.x;
  if (e < NE) {
    int ns = mp[ei[e]], nd = mp[ei[NE + e]];
    if (ns >= 0 && nd >= 0) {
      int p = off[nd] + atomicAdd(&cur[nd], 1);
      el[p] = ns;
    }
  }
}

// single-block exclusive scan, n <= 32768, writes out[0..n]
__global__ __launch_bounds__(1024) void scan_kernel(const int* __restrict__ in,
                                                    int* __restrict__ out, int n) {
  __shared__ int ls[1024];
  int tid = threadIdx.x;
  int per = (n + 1023) >> 10;
  int base = tid * per;
  int s = 0;
  for (int i = 0; i < per; ++i) { int idx = base + i; if (idx < n) s += in[idx]; }
  ls[tid] = s;
  __syncthreads();
  for (int d = 1; d < 1024; d <<= 1) {
    int v = (tid >= d) ? ls[tid - d] : 0;
    __syncthreads();
    ls[tid] += v;
    __syncthreads();
  }
  int excl = (tid == 0) ? 0 : ls[tid - 1];
  for (int i = 0; i < per; ++i) {
    int idx = base + i;
    if (idx < n) { out[idx] = excl; excl += in[idx]; }
  }
  if (tid == 1023) out[n] = ls[1023];
}

// gather-side GCN aggregation: out[node,f] = relu(b[f] + sum_{src in list} t[src,f])
__global__ void agg_kernel(const float* __restrict__ t, const int* __restrict__ off,
                           const int* __restrict__ el, const float* __restrict__ b,
                           float* __restrict__ out, int F) {
  int node = blockIdx.x, f = threadIdx.x;
  int e0 = off[node], e1 = off[node + 1];
  float acc = 0.f;
  for (int j = e0; j < e1; ++j) acc += t[(size_t)el[j] * F + f];
  out[(size_t)node * F + f] = fmaxf(acc + b[f], 0.f);
}

// ---------------- radius neighbors (first K lowest-index within R) + mapset ----------------
__global__ __launch_bounds__(256) void radius_kernel(const float* __restrict__ pos,
                                                     const float* __restrict__ qpos,
                                                     int* __restrict__ cols,
                                                     int* __restrict__ cnt,
                                                     const int* __restrict__ idxf,
                                                     int* __restrict__ mp) {
  const int g = blockIdx.x;
  __shared__ float sx[NPG], sy[NPG], sz[NPG];
  const float* pg = pos + (size_t)g * NPG * 3;
  for (int i = threadIdx.x; i < NPG * 3; i += 256) {
    float v = pg[i]; int node = i / 3, c = i - node * 3;
    if (c == 0) sx[node] = v; else if (c == 1) sy[node] = v; else sz[node] = v;
  }
  __syncthreads();
  int m = g * NS + blockIdx.y * 256 + threadIdx.x;
  mp[idxf[m]] = m;  // fused mapset (threads <-> samples 1:1 over the grid)
  float qx = qpos[(size_t)m * 3], qy = qpos[(size_t)m * 3 + 1], qz = qpos[(size_t)m * 3 + 2];
  int* out = cols + (size_t)m * KN;
  int c = 0;
  for (int i = 0; i < NPG; ++i) {
    float dx = __fsub_rn(sx[i], qx);
    float dy = __fsub_rn(sy[i], qy);
    float dz = __fsub_rn(sz[i], qz);
    float d2 = __fadd_rn(__fadd_rn(__fmul_rn(dx, dx), __fmul_rn(dy, dy)), __fmul_rn(dz, dz));
    if (d2 < 0.16f) {
      out[c++] = i;
      if (c == KN) break;
    }
  }
  cnt[m] = c;
}

// ---------------- PointConv: max over neighbors of [h2[c], p[c]-q] ----------------
__global__ __launch_bounds__(64) void pointconv_kernel(const float* __restrict__ h2,
                                                       const float* __restrict__ pos,
                                                       const float* __restrict__ qpos,
                                                       const int* __restrict__ cols,
                                                       const int* __restrict__ cnt,
                                                       float* __restrict__ xint) {
  int m = blockIdx.x, t = threadIdx.x;
  int g = m / NS;
  int n = cnt[m];
  const int* cl = cols + (size_t)m * KN;
  float m0 = -INFINITY, m1 = -INFINITY, mp = -INFINITY;
  for (int k = 0; k < n; ++k) {
    int c = cl[k];
    size_t base = (size_t)(g * NPG + c);
    m0 = fmaxf(m0, h2[base * 128 + t]);
    m1 = fmaxf(m1, h2[base * 128 + 64 + t]);
    if (t < 3) mp = fmaxf(mp, pos[base * 3 + t]);
  }
  float* xo = xint + (size_t)m * 131;
  xo[t] = m0;
  xo[64 + t] = m1;
  if (t < 3) xo[128 + t] = __fsub_rn(mp, qpos[(size_t)m * 3 + t]);
}

// ---------------- pooling + head ----------------
__global__ void pool_kernel(const float* __restrict__ h3, float* __restrict__ pooled) {
  int g = blockIdx.x, ch = blockIdx.y, f = threadIdx.x;  // 256 threads
  float mx = 0.f;  // h3 >= 0 (relu)
  size_t base = ((size_t)g * NS + (size_t)ch * 256) * 256 + f;
  for (int s = 0; s < 256; ++s) mx = fmaxf(mx, h3[base + (size_t)s * 256]);
  atomicMax((int*)pooled + g * 256 + f, __float_as_int(mx));
}

__global__ void head_kernel(const float* __restrict__ pooled, const float* __restrict__ lw,
                            const float* __restrict__ lb, float* __restrict__ outp) {
  __shared__ float lg[NG * NC];
  int t = threadIdx.x;  // 128 threads
  if (t < NG * NC) {
    int g = t / NC, c = t % NC;
    float acc = lb[c];
    for (int k = 0; k < 256; ++k) acc += pooled[g * 256 + k] * lw[k * NC + c];
    lg[t] = acc;
  }
  __syncthreads();
  if (t < NG) {
    int g = t;
    float mx = -INFINITY;
    for (int c = 0; c < NC; ++c) mx = fmaxf(mx, lg[g * NC + c]);
    float sum = 0.f;
    for (int c = 0; c < NC; ++c) sum += expf(lg[g * NC + c] - mx);
    float lse = logf(sum);
    float ov[NC];
    float mx2 = -INFINITY;
    for (int c = 0; c < NC; ++c) {
      ov[c] = lg[g * NC + c] - mx - lse;
      outp[g * NC + c] = ov[c];
      mx2 = fmaxf(mx2, ov[c]);
    }
    float s2 = 0.f;
    for (int c = 0; c < NC; ++c) s2 += expf(ov[c] - mx2);
    for (int c = 0; c < NC; ++c) outp[NG * NC + g * NC + c] = expf(ov[c] - mx2) / s2;
  }
}

extern "C" void kernel_launch(void* const* d_in, const int* in_sizes, int n_in,
                              void* d_out, int out_size, void* d_ws, size_t ws_size,
                              hipStream_t stream) {
  const float* norm = (const float*)d_in[0];
  const float* pos  = (const float*)d_in[1];
  const float* x    = (const float*)d_in[2];
  const int* ei     = (const int*)d_in[3];   // int32! row0 = src, row1 = dst
  // d_in[4] = batch (int32, unused)
  const float* W1 = (const float*)d_in[5];
  const float* b1 = (const float*)d_in[6];
  const float* W2 = (const float*)d_in[7];
  const float* b2 = (const float*)d_in[8];
  const float* W3 = (const float*)d_in[9];
  const float* b3 = (const float*)d_in[10];
  const float* lw = (const float*)d_in[11];
  const float* lb = (const float*)d_in[12];
  float* outp = (float*)d_out;

  char* w = (char*)d_ws;
  size_t o = 0;
  auto alloc = [&](size_t bytes) -> void* {
    void* p = w + o;
    o = (o + bytes + 255) & ~(size_t)255;
    return p;
  };
  float* A    = (float*)alloc((size_t)NT * 128 * 4);  // t2 -> t3
  float* Bf   = (float*)alloc((size_t)NT * 128 * 4);  // h2 -> h3
  float* T1   = (float*)alloc((size_t)NT * 64 * 4);   // t1 (separate: read while t2 written)
  float* xint = (float*)alloc((size_t)GS * 131 * 4);
  int* cols   = (int*)alloc((size_t)GS * KN * 4);
  int* cnt    = (int*)alloc((size_t)GS * 4);
  int* deg1   = (int*)alloc((size_t)NT * 4);
  int* off1   = (int*)alloc((size_t)(NT + 1) * 4);
  int* cur1   = (int*)alloc((size_t)NT * 4);
  int* el1    = (int*)alloc((size_t)NE * 4);
  int* deg2   = (int*)alloc((size_t)GS * 4);
  int* off2   = (int*)alloc((size_t)(GS + 1) * 4);
  int* cur2   = (int*)alloc((size_t)GS * 4);
  int* el2    = (int*)alloc((size_t)NE * 4);
  int* idxf   = (int*)alloc((size_t)GS * 4);
  float* qpos = (float*)alloc((size_t)GS * 3 * 4);
  int* mapv   = (int*)alloc((size_t)NT * 4);
  float* pooled = (float*)alloc((size_t)NG * 256 * 4);
  int* wctr   = (int*)alloc(64);

  hipMemsetAsync(deg1, 0, (size_t)NT * 4, stream);
  hipMemsetAsync(cur1, 0, (size_t)NT * 4, stream);
  hipMemsetAsync(deg2, 0, (size_t)GS * 4, stream);
  hipMemsetAsync(cur2, 0, (size_t)GS * 4, stream);
  hipMemsetAsync(mapv, 0xFF, (size_t)NT * 4, stream);  // -1
  hipMemsetAsync(pooled, 0, (size_t)NG * 256 * 4, stream);
  hipMemsetAsync(wctr, 0, 64, stream);

  // phase A (cooperative): fps ∥ {feat1,deg1,scan,fill1,agg1+feat2,agg2}
  {
    void* ka[] = {(void*)&pos, (void*)&idxf, (void*)&qpos, (void*)&norm, (void*)&x,
                  (void*)&W1, (void*)&T1, (void*)&ei, (void*)&deg1,
                  (void*)&off1, (void*)&cur1, (void*)&el1,
                  (void*)&b1, (void*)&W2, (void*)&A, (void*)&b2, (void*)&Bf,
                  (void*)&wctr};
    hipLaunchCooperativeKernel((const void*)phaseA_kernel, dim3(8 + NWORK), dim3(256),
                               ka, 0, stream);
  }
  // neighborhoods (radius + fused mapset)
  radius_kernel<<<dim3(NG, NS / 256), 256, 0, stream>>>(pos, qpos, cols, cnt, idxf, mapv);
  pointconv_kernel<<<GS, 64, 0, stream>>>(Bf, pos, qpos, cols, cnt, xint);
  // feat3 + deg2 fused
  featdeg_kernel<<<GS + NE / 256, 256, 0, stream>>>(xint, idxf, norm, pos, x, W3, A,
                                                    ei, mapv, deg2);
  scan_kernel<<<1, 1024, 0, stream>>>(deg2, off2, GS);
  fill2_kernel<<<NE / 256, 256, 0, stream>>>(ei, mapv, off2, cur2, el2);
  // layer 3
  agg_kernel<<<GS, 256, 0, stream>>>(A, off2, el2, b3, Bf, 256);
  // pool + head
  pool_kernel<<<dim3(NG, NS / 256), 256, 0, stream>>>(Bf, pooled);
  head_kernel<<<1, 128, 0, stream>>>(pooled, lw, lb, outp);
}